// Round 10
// baseline (406.878 us; speedup 1.0000x reference)
//
#include <hip/hip_runtime.h>

#define N_NODES 100000
#define N_EDGES 1200000
#define DIM 64
#define N_GRAPHS 128
#define N_LAYERS 5

#define NBUCKETS 782          // ceil(100000/128)
#define BCAP 2048             // per-bucket capacity (mean 1534, +13 sigma)
#define CHUNK 8192            // edges per bin block

#define POOL_CH 196
#define POOL_BLOCKS ((N_NODES + POOL_CH - 1) / POOL_CH)

#define WSTR 72               // bf16 LDS row stride

typedef unsigned short ushort_t;
typedef unsigned int uint_t;
typedef __attribute__((ext_vector_type(8))) short short8v;   // 8 bf16 = 4 VGPR
typedef __attribute__((ext_vector_type(4))) float float4v;

__device__ __forceinline__ float bf2f(uint_t s) {
  return __uint_as_float(s << 16);
}
__device__ __forceinline__ ushort_t f2bf(float f) {
  uint_t u = __float_as_uint(f);
  uint_t r = u + 0x7fffu + ((u >> 16) & 1u);   // RNE
  return (ushort_t)(r >> 16);
}
__device__ __forceinline__ uint_t pack2(float a, float b) {
  return (uint_t)f2bf(a) | ((uint_t)f2bf(b) << 16);
}

// ---------------- fp32 -> bf16 convert (x only, once) ----------------

__global__ __launch_bounds__(256) void conv_kernel(const float* __restrict__ x,
                                                   ushort_t* __restrict__ xb) {
  int i = blockIdx.x * 256 + threadIdx.x;
  int base = i * 8;
  if (base >= N_NODES * DIM) return;
  float4 a = *(const float4*)(x + base);
  float4 b = *(const float4*)(x + base + 4);
  uint4 o;
  o.x = pack2(a.x, a.y);
  o.y = pack2(a.z, a.w);
  o.z = pack2(b.x, b.y);
  o.w = pack2(b.z, b.w);
  *(uint4*)(xb + base) = o;
}

// ---------------- weight prep (once): transpose to bf16, fold BN into W1 ----------------
// W1bT[l][n][k] = bf16(W1[l][k][n] * gam[l][n] / sqrt(1+eps)); W2bT[l][n][k] = bf16(W2[l][k][n])
// b1p[l][n] = b1*sc + beta.

__global__ __launch_bounds__(256) void wconv_kernel(const float* __restrict__ W1s,
                                                    const float* __restrict__ b1s,
                                                    const float* __restrict__ gammas,
                                                    const float* __restrict__ betas,
                                                    const float* __restrict__ W2s,
                                                    ushort_t* __restrict__ W1bT,
                                                    ushort_t* __restrict__ W2bT,
                                                    float* __restrict__ b1p) {
  int idx = blockIdx.x * 256 + threadIdx.x;
  if (idx >= N_LAYERS * 4096) return;
  int l = idx >> 12, rem = idx & 4095;
  int n = rem >> 6, k = rem & 63;
  const float BNR = 0.99999500003749971893f;   // 1/sqrt(1+1e-5)
  float sc = gammas[l * 64 + n] * BNR;
  W1bT[(size_t)l * 4096 + n * 64 + k] = f2bf(W1s[(size_t)l * 4096 + k * 64 + n] * sc);
  W2bT[(size_t)l * 4096 + n * 64 + k] = f2bf(W2s[(size_t)l * 4096 + k * 64 + n]);
  if (k == 0) b1p[l * 64 + n] = fmaf(b1s[l * 64 + n], sc, betas[l * 64 + n]);
}

// ---------------- CSR build stage 1: LDS multisplit into 782 buckets ----------------

__global__ __launch_bounds__(256) void bin_kernel(const int* __restrict__ src,
                                                  const int* __restrict__ dst,
                                                  int* __restrict__ gCursor,
                                                  uint_t* __restrict__ gPairs) {
  __shared__ int hist[NBUCKETS];
  __shared__ int lstart[NBUCKETS];
  __shared__ int lcur[NBUCKETS];
  __shared__ int gbase[NBUCKETS];
  __shared__ uint_t pairbuf[CHUNK];
  __shared__ ushort_t bidbuf[CHUNK];
  __shared__ int wsum[4];

  const int t = threadIdx.x;
  const int e0 = blockIdx.x * CHUNK;
  const int ecnt = min(CHUNK, N_EDGES - e0);

  for (int i = t; i < NBUCKETS; i += 256) hist[i] = 0;
  __syncthreads();

  for (int i = t; i < ecnt; i += 256) {
    int d = dst[e0 + i];
    atomicAdd(&hist[d >> 7], 1);
  }
  __syncthreads();

  const int base4 = t * 4;
  int h0 = 0, h1 = 0, h2 = 0, h3 = 0;
  if (base4 + 0 < NBUCKETS) h0 = hist[base4 + 0];
  if (base4 + 1 < NBUCKETS) h1 = hist[base4 + 1];
  if (base4 + 2 < NBUCKETS) h2 = hist[base4 + 2];
  if (base4 + 3 < NBUCKETS) h3 = hist[base4 + 3];
  int tsum = h0 + h1 + h2 + h3;
  int lane = t & 63, wid = t >> 6;
  int inc = tsum;
  #pragma unroll
  for (int off = 1; off < 64; off <<= 1) {
    int v = __shfl_up(inc, off);
    if (lane >= off) inc += v;
  }
  if (lane == 63) wsum[wid] = inc;
  __syncthreads();
  int wadd = 0;
  for (int w = 0; w < wid; ++w) wadd += wsum[w];
  int ex = wadd + inc - tsum;
  if (base4 + 0 < NBUCKETS) { lstart[base4 + 0] = ex; lcur[base4 + 0] = ex; } ex += h0;
  if (base4 + 1 < NBUCKETS) { lstart[base4 + 1] = ex; lcur[base4 + 1] = ex; } ex += h1;
  if (base4 + 2 < NBUCKETS) { lstart[base4 + 2] = ex; lcur[base4 + 2] = ex; } ex += h2;
  if (base4 + 3 < NBUCKETS) { lstart[base4 + 3] = ex; lcur[base4 + 3] = ex; }
  __syncthreads();

  for (int i = t; i < ecnt; i += 256) {
    int s = src[e0 + i];
    int d = dst[e0 + i];
    int b = d >> 7;
    int p = atomicAdd(&lcur[b], 1);
    pairbuf[p] = (uint_t)s | ((uint_t)(d & 127) << 17);
    bidbuf[p] = (ushort_t)b;
  }
  __syncthreads();

  for (int b = t; b < NBUCKETS; b += 256) {
    int cnt = lcur[b] - lstart[b];
    gbase[b] = cnt ? atomicAdd(&gCursor[b], cnt) : 0;
  }
  __syncthreads();

  for (int i = t; i < ecnt; i += 256) {
    int b = bidbuf[i];
    int pos = gbase[b] + (i - lstart[b]);
    if (pos < BCAP) gPairs[b * BCAP + pos] = pairbuf[i];
  }
}

__global__ __launch_bounds__(1024) void bscan_kernel(const int* __restrict__ gCursor,
                                                     int* __restrict__ bucketBase) {
  __shared__ int sm[1024];
  int t = threadIdx.x;
  int v = (t < NBUCKETS) ? min(gCursor[t], BCAP) : 0;
  sm[t] = v;
  __syncthreads();
  for (int off = 1; off < 1024; off <<= 1) {
    int x = (t >= off) ? sm[t - off] : 0;
    __syncthreads();
    sm[t] += x;
    __syncthreads();
  }
  bucketBase[t] = sm[t] - v;
  if (t == NBUCKETS - 1) bucketBase[NBUCKETS] = sm[t];
}

// ---------------- stage 2: per-bucket counting sort by (dstLocal, srcCoarse) ----------------

__global__ __launch_bounds__(256) void csort_kernel(const int* __restrict__ gCursor,
                                                    const int* __restrict__ bucketBase,
                                                    const uint_t* __restrict__ gPairs,
                                                    int* __restrict__ rowptr,
                                                    int* __restrict__ ssrc) {
  __shared__ uint_t vals[BCAP];
  __shared__ int ssl[BCAP];
  __shared__ int hist[1024];
  __shared__ int cur[1024];
  __shared__ int wsum[4];

  const int b = blockIdx.x, t = threadIdx.x;
  const int cnt = min(gCursor[b], BCAP);
  const int base = bucketBase[b];
  const int n0 = b << 7;
  const int nn = min(128, N_NODES - n0);

  for (int i = t; i < 1024; i += 256) hist[i] = 0;
  __syncthreads();
  for (int i = t; i < cnt; i += 256) {
    uint_t v = gPairs[b * BCAP + i];
    vals[i] = v;
    int bin = (int)((v >> 17) & 127u) * 8 + (int)((v & 0x1FFFFu) >> 14);
    atomicAdd(&hist[bin], 1);
  }
  __syncthreads();

  const int b4 = t * 4;
  int h0 = hist[b4], h1 = hist[b4 + 1], h2 = hist[b4 + 2], h3 = hist[b4 + 3];
  int tsum = h0 + h1 + h2 + h3;
  int lane = t & 63, wid = t >> 6;
  int inc = tsum;
  #pragma unroll
  for (int off = 1; off < 64; off <<= 1) {
    int v = __shfl_up(inc, off);
    if (lane >= off) inc += v;
  }
  if (lane == 63) wsum[wid] = inc;
  __syncthreads();
  int wadd = 0;
  for (int w = 0; w < wid; ++w) wadd += wsum[w];
  int ex = wadd + inc - tsum;
  #pragma unroll
  for (int q = 0; q < 4; ++q) {
    int bin = b4 + q;
    cur[bin] = ex;
    if ((bin & 7) == 0) {
      int dl = bin >> 3;
      if (dl < nn) rowptr[n0 + dl] = base + ex;
    }
    ex += hist[bin];
  }
  if (b == NBUCKETS - 1 && t == 0) rowptr[N_NODES] = base + cnt;
  __syncthreads();

  for (int i = t; i < cnt; i += 256) {
    uint_t v = vals[i];
    int bin = (int)((v >> 17) & 127u) * 8 + (int)((v & 0x1FFFFu) >> 14);
    int p = atomicAdd(&cur[bin], 1);
    ssl[p] = (int)(v & 0x1FFFFu);
  }
  __syncthreads();
  for (int i = t; i < cnt; i += 256) ssrc[base + i] = ssl[i];
}

// ---------------- aggregation: z = h + sum h_j, 4 nodes per wave ----------------
// lane l: edge slot l>>3 (0..7), dims ((l&7)*8) as uint4. Four independent
// gathers in flight per iteration (one per node).

__global__ __launch_bounds__(256) void agg_kernel(const ushort_t* __restrict__ h,
                                                  const int* __restrict__ rowptr,
                                                  const int* __restrict__ ssrc,
                                                  ushort_t* __restrict__ zb) {
  int quad = blockIdx.x * 4 + (threadIdx.x >> 6);
  int l = threadIdx.x & 63;
  int n0 = quad * 4;
  if (n0 >= N_NODES) return;          // N_NODES % 4 == 0
  int sub = l >> 3;
  int dp = (l & 7) << 3;

  float a[4][8];
  #pragma unroll
  for (int q = 0; q < 4; ++q)
    #pragma unroll
    for (int i = 0; i < 8; ++i) a[q][i] = 0.f;

  int rp0 = rowptr[n0 + 0], rp1 = rowptr[n0 + 1], rp2 = rowptr[n0 + 2];
  int rp3 = rowptr[n0 + 3], rp4 = rowptr[n0 + 4];
  int s_[4] = {rp0, rp1, rp2, rp3};
  int e_[4] = {rp1, rp2, rp3, rp4};

  // self rows: sub-group q loads node n0+q
  if (sub < 4) {
    uint4 r = *(const uint4*)(h + (size_t)(n0 + sub) * DIM + dp);
    a[sub][0] = bf2f(r.x & 0xffffu); a[sub][1] = bf2f(r.x >> 16);
    a[sub][2] = bf2f(r.y & 0xffffu); a[sub][3] = bf2f(r.y >> 16);
    a[sub][4] = bf2f(r.z & 0xffffu); a[sub][5] = bf2f(r.z >> 16);
    a[sub][6] = bf2f(r.w & 0xffffu); a[sub][7] = bf2f(r.w >> 16);
  }

  int md = max(max(e_[0] - s_[0], e_[1] - s_[1]), max(e_[2] - s_[2], e_[3] - s_[3]));
  int iters = (md + 7) >> 3;
  for (int it = 0; it < iters; ++it) {
    uint4 r[4];
    #pragma unroll
    for (int q = 0; q < 4; ++q) {
      int j = s_[q] + it * 8 + sub;
      r[q] = make_uint4(0u, 0u, 0u, 0u);
      if (j < e_[q]) {
        int u = ssrc[j];
        r[q] = *(const uint4*)(h + (size_t)u * DIM + dp);
      }
    }
    #pragma unroll
    for (int q = 0; q < 4; ++q) {
      a[q][0] += bf2f(r[q].x & 0xffffu); a[q][1] += bf2f(r[q].x >> 16);
      a[q][2] += bf2f(r[q].y & 0xffffu); a[q][3] += bf2f(r[q].y >> 16);
      a[q][4] += bf2f(r[q].z & 0xffffu); a[q][5] += bf2f(r[q].z >> 16);
      a[q][6] += bf2f(r[q].w & 0xffffu); a[q][7] += bf2f(r[q].w >> 16);
    }
  }

  #pragma unroll
  for (int q = 0; q < 4; ++q)
    #pragma unroll
    for (int i = 0; i < 8; ++i) {
      a[q][i] += __shfl_xor(a[q][i], 8);
      a[q][i] += __shfl_xor(a[q][i], 16);
      a[q][i] += __shfl_xor(a[q][i], 32);
    }

  if (sub < 4) {
    uint4 o;
    o.x = pack2(a[sub][0], a[sub][1]);
    o.y = pack2(a[sub][2], a[sub][3]);
    o.z = pack2(a[sub][4], a[sub][5]);
    o.w = pack2(a[sub][6], a[sub][7]);
    *(uint4*)(zb + (size_t)(n0 + sub) * DIM + dp) = o;
  }
}

// ---------------- MFMA MLP: pre-transposed bf16 weights, BN folded ----------------

__global__ __launch_bounds__(256) void mlp_kernel(const ushort_t* __restrict__ zb,
                                                  ushort_t* __restrict__ hout,
                                                  const ushort_t* __restrict__ W1bT,
                                                  const float* __restrict__ b1p,
                                                  const ushort_t* __restrict__ W2bT,
                                                  const float* __restrict__ b2) {
  __shared__ ushort_t zs[128 * WSTR];
  __shared__ ushort_t wt1[64 * WSTR];
  __shared__ ushort_t wt2[64 * WSTR];

  const int t = threadIdx.x;
  const int base = blockIdx.x * 128;

  #pragma unroll
  for (int i = 0; i < 4; ++i) {
    int f = i * 256 + t;
    int row = f >> 3, seg = (f & 7) << 3;
    int gn = base + row;
    if (gn >= N_NODES) gn = N_NODES - 1;
    *(uint4*)(zs + row * WSTR + seg) = *(const uint4*)(zb + (size_t)gn * DIM + seg);
  }
  #pragma unroll
  for (int i = 0; i < 2; ++i) {
    int f = i * 256 + t;                 // 512 uint4 slots per matrix
    int n = f >> 3, kseg = (f & 7) << 3;
    *(uint4*)(wt1 + n * WSTR + kseg) = *(const uint4*)(W1bT + n * 64 + kseg);
    *(uint4*)(wt2 + n * WSTR + kseg) = *(const uint4*)(W2bT + n * 64 + kseg);
  }
  __syncthreads();

  const int lane = t & 63;
  const int w = t >> 6;
  const int lr = lane & 15;
  const int kc = lane >> 4;

  float o_[4], bb_[4];
  #pragma unroll
  for (int nt = 0; nt < 4; ++nt) {
    int od = nt * 16 + lr;
    o_[nt] = b1p[od];
    bb_[nt] = b2[od];
  }

  float4v acc[2][4];
  #pragma unroll
  for (int mt = 0; mt < 2; ++mt)
    #pragma unroll
    for (int nt = 0; nt < 4; ++nt)
      acc[mt][nt] = (float4v){0.f, 0.f, 0.f, 0.f};

  #pragma unroll
  for (int k0 = 0; k0 < 2; ++k0) {
    short8v bfr[4];
    #pragma unroll
    for (int nt = 0; nt < 4; ++nt)
      bfr[nt] = *(short8v*)(wt1 + (nt * 16 + lr) * WSTR + k0 * 32 + kc * 8);
    #pragma unroll
    for (int mt = 0; mt < 2; ++mt) {
      short8v afr = *(short8v*)(zs + ((w * 2 + mt) * 16 + lr) * WSTR + k0 * 32 + kc * 8);
      #pragma unroll
      for (int nt = 0; nt < 4; ++nt)
        acc[mt][nt] = __builtin_amdgcn_mfma_f32_16x16x32_bf16(afr, bfr[nt], acc[mt][nt], 0, 0, 0);
    }
  }

  #pragma unroll
  for (int mt = 0; mt < 2; ++mt)
    #pragma unroll
    for (int nt = 0; nt < 4; ++nt)
      #pragma unroll
      for (int r = 0; r < 4; ++r) {
        float v = acc[mt][nt][r] + o_[nt];
        v = v > 0.f ? v : 0.f;
        int node = (w * 2 + mt) * 16 + kc * 4 + r;
        zs[node * WSTR + nt * 16 + lr] = f2bf(v);
      }

  #pragma unroll
  for (int mt = 0; mt < 2; ++mt)
    #pragma unroll
    for (int nt = 0; nt < 4; ++nt)
      acc[mt][nt] = (float4v){0.f, 0.f, 0.f, 0.f};

  #pragma unroll
  for (int k0 = 0; k0 < 2; ++k0) {
    short8v bfr[4];
    #pragma unroll
    for (int nt = 0; nt < 4; ++nt)
      bfr[nt] = *(short8v*)(wt2 + (nt * 16 + lr) * WSTR + k0 * 32 + kc * 8);
    #pragma unroll
    for (int mt = 0; mt < 2; ++mt) {
      short8v afr = *(short8v*)(zs + ((w * 2 + mt) * 16 + lr) * WSTR + k0 * 32 + kc * 8);
      #pragma unroll
      for (int nt = 0; nt < 4; ++nt)
        acc[mt][nt] = __builtin_amdgcn_mfma_f32_16x16x32_bf16(afr, bfr[nt], acc[mt][nt], 0, 0, 0);
    }
  }

  #pragma unroll
  for (int mt = 0; mt < 2; ++mt)
    #pragma unroll
    for (int nt = 0; nt < 4; ++nt)
      #pragma unroll
      for (int r = 0; r < 4; ++r) {
        float v = acc[mt][nt][r] + bb_[nt];
        v = v > 0.f ? v : 0.f;
        int node = (w * 2 + mt) * 16 + kc * 4 + r;
        zs[node * WSTR + nt * 16 + lr] = f2bf(v);
      }
  __syncthreads();

  #pragma unroll
  for (int i = 0; i < 4; ++i) {
    int f = i * 256 + t;
    int row = f >> 3, seg = (f & 7) << 3;
    int gn = base + row;
    if (gn < N_NODES)
      *(uint4*)(hout + (size_t)gn * DIM + seg) = *(const uint4*)(zs + row * WSTR + seg);
  }
}

// ---------------- pool: partial sums (batch sorted) + tiny head ----------------

__global__ __launch_bounds__(256) void pool_partial_kernel(const ushort_t* __restrict__ h,
                                                           const int* __restrict__ batch,
                                                           float* __restrict__ pooled) {
  int r0 = blockIdx.x * POOL_CH;
  int rend = min(r0 + POOL_CH, N_NODES);
  int w = threadIdx.x >> 6, d = threadIdx.x & 63;
  float acc = 0.f;
  int curg = -1;
  for (int i = r0 + w; i < rend; i += 4) {
    int g = batch[i];
    if (g != curg) {
      if (curg >= 0) atomicAdd(&pooled[curg * DIM + d], acc);
      acc = 0.f;
      curg = g;
    }
    acc += bf2f((uint_t)h[i * DIM + d]);
  }
  if (curg >= 0) atomicAdd(&pooled[curg * DIM + d], acc);
}

__global__ __launch_bounds__(256) void head_kernel(const float* __restrict__ pooled,
                                                   const float* __restrict__ lw,
                                                   const float* __restrict__ lb,
                                                   float* __restrict__ out) {
  int idx = blockIdx.x * 256 + threadIdx.x;
  if (idx >= N_GRAPHS * DIM) return;
  int g = idx >> 6, d = idx & 63;
  float o = lb[d];
  #pragma unroll 8
  for (int k = 0; k < 64; ++k) o = fmaf(pooled[g * 64 + k], lw[k * 64 + d], o);
  out[idx] = fmaxf(o, 0.f);
}

// ---------------- host ----------------

extern "C" void kernel_launch(void* const* d_in, const int* in_sizes, int n_in,
                              void* d_out, int out_size, void* d_ws, size_t ws_size,
                              hipStream_t stream) {
  const float* x      = (const float*)d_in[0];
  const int*   ei     = (const int*)d_in[1];
  const int*   srcp   = ei;
  const int*   dstp   = ei + N_EDGES;
  const int*   batch  = (const int*)d_in[2];
  const float* W1s    = (const float*)d_in[3];
  const float* b1s    = (const float*)d_in[4];
  const float* gammas = (const float*)d_in[5];
  const float* betas  = (const float*)d_in[6];
  const float* W2s    = (const float*)d_in[7];
  const float* b2s    = (const float*)d_in[8];
  const float* lin1_w = (const float*)d_in[9];
  const float* lin1_b = (const float*)d_in[10];

  char* p = (char*)d_ws;
  ushort_t* xb     = (ushort_t*)p; p += (size_t)N_NODES * DIM * 2;      // 12.8 MB
  ushort_t* h1     = (ushort_t*)p; p += (size_t)N_NODES * DIM * 2;      // 12.8 MB
  ushort_t* zbuf   = (ushort_t*)p; p += (size_t)N_NODES * DIM * 2;      // 12.8 MB
  uint_t*   gPairs = (uint_t*)p;   p += (size_t)NBUCKETS * BCAP * 4;    // 6.4 MB
  int*      ssrc   = (int*)p;      p += (size_t)N_EDGES * 4;            // 4.8 MB
  int*      rowptr = (int*)p;      p += 100352 * sizeof(int);
  int*      gCursor    = (int*)p;  p += 4096;
  int*      bucketBase = (int*)p;  p += 4096;
  ushort_t* W1bT   = (ushort_t*)p; p += N_LAYERS * 4096 * 2;
  ushort_t* W2bT   = (ushort_t*)p; p += N_LAYERS * 4096 * 2;
  float*    b1p    = (float*)p;    p += N_LAYERS * 64 * sizeof(float);
  float*    pooled = (float*)p;

  hipMemsetAsync(gCursor, 0, 1024 * sizeof(int), stream);
  hipMemsetAsync(pooled, 0, N_GRAPHS * DIM * sizeof(float), stream);
  conv_kernel<<<(N_NODES * DIM / 8 + 255) / 256, 256, 0, stream>>>(x, xb);
  wconv_kernel<<<(N_LAYERS * 4096 + 255) / 256, 256, 0, stream>>>(
      W1s, b1s, gammas, betas, W2s, W1bT, W2bT, b1p);

  const int BIN_BLOCKS = (N_EDGES + CHUNK - 1) / CHUNK;   // 147
  bin_kernel<<<BIN_BLOCKS, 256, 0, stream>>>(srcp, dstp, gCursor, gPairs);
  bscan_kernel<<<1, 1024, 0, stream>>>(gCursor, bucketBase);
  csort_kernel<<<NBUCKETS, 256, 0, stream>>>(gCursor, bucketBase, gPairs, rowptr, ssrc);

  const int AGG_BLOCKS = (N_NODES / 4 + 3) / 4;      // 6250 (quads, 4 per block)
  const int MLP_BLOCKS = NBUCKETS;                   // 782

  const ushort_t* hin = xb;
  for (int l = 0; l < N_LAYERS; ++l) {
    ushort_t* hout = (l & 1) ? xb : h1;
    agg_kernel<<<AGG_BLOCKS, 256, 0, stream>>>(hin, rowptr, ssrc, zbuf);
    mlp_kernel<<<MLP_BLOCKS, 256, 0, stream>>>(zbuf, hout,
        W1bT + (size_t)l * 4096, b1p + (size_t)l * 64,
        W2bT + (size_t)l * 4096, b2s + (size_t)l * DIM);
    hin = hout;
  }

  pool_partial_kernel<<<POOL_BLOCKS, 256, 0, stream>>>(h1, batch, pooled);
  head_kernel<<<(N_GRAPHS * DIM + 255) / 256, 256, 0, stream>>>(pooled, lin1_w, lin1_b, (float*)d_out);
}

// Round 11
// 291.998 us; speedup vs baseline: 1.3934x; 1.3934x over previous
//
#include <hip/hip_runtime.h>

#define N_NODES 100000
#define N_EDGES 1200000
#define DIM 64
#define N_GRAPHS 128
#define N_LAYERS 5

#define NBUCKETS 782          // ceil(100000/128)
#define BCAP 2048             // per-bucket capacity (mean 1534, +13 sigma)
#define CHUNK 8192            // edges per bin block

#define POOL_CH 196
#define POOL_BLOCKS ((N_NODES + POOL_CH - 1) / POOL_CH)

#define WSTR 72               // bf16 LDS row stride

typedef unsigned short ushort_t;
typedef unsigned int uint_t;
typedef __attribute__((ext_vector_type(8))) short short8v;   // 8 bf16 = 4 VGPR
typedef __attribute__((ext_vector_type(4))) float float4v;

__device__ __forceinline__ float bf2f(uint_t s) {
  return __uint_as_float(s << 16);
}
__device__ __forceinline__ ushort_t f2bf(float f) {
  uint_t u = __float_as_uint(f);
  uint_t r = u + 0x7fffu + ((u >> 16) & 1u);   // RNE
  return (ushort_t)(r >> 16);
}
__device__ __forceinline__ uint_t pack2(float a, float b) {
  return (uint_t)f2bf(a) | ((uint_t)f2bf(b) << 16);
}

// ---------------- fp32 -> bf16 convert (x only, once) ----------------

__global__ __launch_bounds__(256) void conv_kernel(const float* __restrict__ x,
                                                   ushort_t* __restrict__ xb) {
  int i = blockIdx.x * 256 + threadIdx.x;
  int base = i * 8;
  if (base >= N_NODES * DIM) return;
  float4 a = *(const float4*)(x + base);
  float4 b = *(const float4*)(x + base + 4);
  uint4 o;
  o.x = pack2(a.x, a.y);
  o.y = pack2(a.z, a.w);
  o.z = pack2(b.x, b.y);
  o.w = pack2(b.z, b.w);
  *(uint4*)(xb + base) = o;
}

// ---------------- weight prep (once): transpose to bf16, fold BN into W1 ----------------

__global__ __launch_bounds__(256) void wconv_kernel(const float* __restrict__ W1s,
                                                    const float* __restrict__ b1s,
                                                    const float* __restrict__ gammas,
                                                    const float* __restrict__ betas,
                                                    const float* __restrict__ W2s,
                                                    ushort_t* __restrict__ W1bT,
                                                    ushort_t* __restrict__ W2bT,
                                                    float* __restrict__ b1p) {
  int idx = blockIdx.x * 256 + threadIdx.x;
  if (idx >= N_LAYERS * 4096) return;
  int l = idx >> 12, rem = idx & 4095;
  int n = rem >> 6, k = rem & 63;
  const float BNR = 0.99999500003749971893f;   // 1/sqrt(1+1e-5)
  float sc = gammas[l * 64 + n] * BNR;
  W1bT[(size_t)l * 4096 + n * 64 + k] = f2bf(W1s[(size_t)l * 4096 + k * 64 + n] * sc);
  W2bT[(size_t)l * 4096 + n * 64 + k] = f2bf(W2s[(size_t)l * 4096 + k * 64 + n]);
  if (k == 0) b1p[l * 64 + n] = fmaf(b1s[l * 64 + n], sc, betas[l * 64 + n]);
}

// ---------------- CSR build stage 1: LDS multisplit into 782 buckets ----------------

__global__ __launch_bounds__(256) void bin_kernel(const int* __restrict__ src,
                                                  const int* __restrict__ dst,
                                                  int* __restrict__ gCursor,
                                                  uint_t* __restrict__ gPairs) {
  __shared__ int hist[NBUCKETS];
  __shared__ int lstart[NBUCKETS];
  __shared__ int lcur[NBUCKETS];
  __shared__ int gbase[NBUCKETS];
  __shared__ uint_t pairbuf[CHUNK];
  __shared__ ushort_t bidbuf[CHUNK];
  __shared__ int wsum[4];

  const int t = threadIdx.x;
  const int e0 = blockIdx.x * CHUNK;
  const int ecnt = min(CHUNK, N_EDGES - e0);

  for (int i = t; i < NBUCKETS; i += 256) hist[i] = 0;
  __syncthreads();

  for (int i = t; i < ecnt; i += 256) {
    int d = dst[e0 + i];
    atomicAdd(&hist[d >> 7], 1);
  }
  __syncthreads();

  const int base4 = t * 4;
  int h0 = 0, h1 = 0, h2 = 0, h3 = 0;
  if (base4 + 0 < NBUCKETS) h0 = hist[base4 + 0];
  if (base4 + 1 < NBUCKETS) h1 = hist[base4 + 1];
  if (base4 + 2 < NBUCKETS) h2 = hist[base4 + 2];
  if (base4 + 3 < NBUCKETS) h3 = hist[base4 + 3];
  int tsum = h0 + h1 + h2 + h3;
  int lane = t & 63, wid = t >> 6;
  int inc = tsum;
  #pragma unroll
  for (int off = 1; off < 64; off <<= 1) {
    int v = __shfl_up(inc, off);
    if (lane >= off) inc += v;
  }
  if (lane == 63) wsum[wid] = inc;
  __syncthreads();
  int wadd = 0;
  for (int w = 0; w < wid; ++w) wadd += wsum[w];
  int ex = wadd + inc - tsum;
  if (base4 + 0 < NBUCKETS) { lstart[base4 + 0] = ex; lcur[base4 + 0] = ex; } ex += h0;
  if (base4 + 1 < NBUCKETS) { lstart[base4 + 1] = ex; lcur[base4 + 1] = ex; } ex += h1;
  if (base4 + 2 < NBUCKETS) { lstart[base4 + 2] = ex; lcur[base4 + 2] = ex; } ex += h2;
  if (base4 + 3 < NBUCKETS) { lstart[base4 + 3] = ex; lcur[base4 + 3] = ex; }
  __syncthreads();

  for (int i = t; i < ecnt; i += 256) {
    int s = src[e0 + i];
    int d = dst[e0 + i];
    int b = d >> 7;
    int p = atomicAdd(&lcur[b], 1);
    pairbuf[p] = (uint_t)s | ((uint_t)(d & 127) << 17);
    bidbuf[p] = (ushort_t)b;
  }
  __syncthreads();

  for (int b = t; b < NBUCKETS; b += 256) {
    int cnt = lcur[b] - lstart[b];
    gbase[b] = cnt ? atomicAdd(&gCursor[b], cnt) : 0;
  }
  __syncthreads();

  for (int i = t; i < ecnt; i += 256) {
    int b = bidbuf[i];
    int pos = gbase[b] + (i - lstart[b]);
    if (pos < BCAP) gPairs[b * BCAP + pos] = pairbuf[i];
  }
}

__global__ __launch_bounds__(1024) void bscan_kernel(const int* __restrict__ gCursor,
                                                     int* __restrict__ bucketBase) {
  __shared__ int sm[1024];
  int t = threadIdx.x;
  int v = (t < NBUCKETS) ? min(gCursor[t], BCAP) : 0;
  sm[t] = v;
  __syncthreads();
  for (int off = 1; off < 1024; off <<= 1) {
    int x = (t >= off) ? sm[t - off] : 0;
    __syncthreads();
    sm[t] += x;
    __syncthreads();
  }
  bucketBase[t] = sm[t] - v;
  if (t == NBUCKETS - 1) bucketBase[NBUCKETS] = sm[t];
}

// ---------------- stage 2: per-bucket counting sort by (dstLocal, srcCoarse) ----------------

__global__ __launch_bounds__(256) void csort_kernel(const int* __restrict__ gCursor,
                                                    const int* __restrict__ bucketBase,
                                                    const uint_t* __restrict__ gPairs,
                                                    int* __restrict__ rowptr,
                                                    int* __restrict__ ssrc) {
  __shared__ uint_t vals[BCAP];
  __shared__ int ssl[BCAP];
  __shared__ int hist[1024];
  __shared__ int cur[1024];
  __shared__ int wsum[4];

  const int b = blockIdx.x, t = threadIdx.x;
  const int cnt = min(gCursor[b], BCAP);
  const int base = bucketBase[b];
  const int n0 = b << 7;
  const int nn = min(128, N_NODES - n0);

  for (int i = t; i < 1024; i += 256) hist[i] = 0;
  __syncthreads();
  for (int i = t; i < cnt; i += 256) {
    uint_t v = gPairs[b * BCAP + i];
    vals[i] = v;
    int bin = (int)((v >> 17) & 127u) * 8 + (int)((v & 0x1FFFFu) >> 14);
    atomicAdd(&hist[bin], 1);
  }
  __syncthreads();

  const int b4 = t * 4;
  int h0 = hist[b4], h1 = hist[b4 + 1], h2 = hist[b4 + 2], h3 = hist[b4 + 3];
  int tsum = h0 + h1 + h2 + h3;
  int lane = t & 63, wid = t >> 6;
  int inc = tsum;
  #pragma unroll
  for (int off = 1; off < 64; off <<= 1) {
    int v = __shfl_up(inc, off);
    if (lane >= off) inc += v;
  }
  if (lane == 63) wsum[wid] = inc;
  __syncthreads();
  int wadd = 0;
  for (int w = 0; w < wid; ++w) wadd += wsum[w];
  int ex = wadd + inc - tsum;
  #pragma unroll
  for (int q = 0; q < 4; ++q) {
    int bin = b4 + q;
    cur[bin] = ex;
    if ((bin & 7) == 0) {
      int dl = bin >> 3;
      if (dl < nn) rowptr[n0 + dl] = base + ex;
    }
    ex += hist[bin];
  }
  if (b == NBUCKETS - 1 && t == 0) rowptr[N_NODES] = base + cnt;
  __syncthreads();

  for (int i = t; i < cnt; i += 256) {
    uint_t v = vals[i];
    int bin = (int)((v >> 17) & 127u) * 8 + (int)((v & 0x1FFFFu) >> 14);
    int p = atomicAdd(&cur[bin], 1);
    ssl[p] = (int)(v & 0x1FFFFu);
  }
  __syncthreads();
  for (int i = t; i < cnt; i += 256) ssrc[base + i] = ssl[i];
}

// ---------------- aggregation: z = h + sum h_j, 2 nodes per wave (round-9 proven) ----------------

__global__ __launch_bounds__(256) void agg_kernel(const ushort_t* __restrict__ h,
                                                  const int* __restrict__ rowptr,
                                                  const int* __restrict__ ssrc,
                                                  ushort_t* __restrict__ zb) {
  int pair = blockIdx.x * 4 + (threadIdx.x >> 6);
  int l = threadIdx.x & 63;
  int n0 = pair * 2;
  if (n0 >= N_NODES) return;
  int n1 = n0 + 1;                      // N even -> always < N_NODES
  int sub = l >> 3;
  int dp = (l & 7) << 3;

  float a0[8], a1[8];
  #pragma unroll
  for (int i = 0; i < 8; ++i) { a0[i] = 0.f; a1[i] = 0.f; }

  int s0 = rowptr[n0], e0 = rowptr[n0 + 1];
  int s1 = e0,         e1 = rowptr[n1 + 1];   // rowptr contiguous

  if (sub == 0) {
    uint4 r = *(const uint4*)(h + (size_t)n0 * DIM + dp);
    uint4 q = *(const uint4*)(h + (size_t)n1 * DIM + dp);
    a0[0] = bf2f(r.x & 0xffffu); a0[1] = bf2f(r.x >> 16);
    a0[2] = bf2f(r.y & 0xffffu); a0[3] = bf2f(r.y >> 16);
    a0[4] = bf2f(r.z & 0xffffu); a0[5] = bf2f(r.z >> 16);
    a0[6] = bf2f(r.w & 0xffffu); a0[7] = bf2f(r.w >> 16);
    a1[0] = bf2f(q.x & 0xffffu); a1[1] = bf2f(q.x >> 16);
    a1[2] = bf2f(q.y & 0xffffu); a1[3] = bf2f(q.y >> 16);
    a1[4] = bf2f(q.z & 0xffffu); a1[5] = bf2f(q.z >> 16);
    a1[6] = bf2f(q.w & 0xffffu); a1[7] = bf2f(q.w >> 16);
  }

  int d0 = e0 - s0, d1 = e1 - s1;
  int iters = (max(d0, d1) + 7) >> 3;
  for (int it = 0; it < iters; ++it) {
    int j0 = s0 + it * 8 + sub;
    int j1 = s1 + it * 8 + sub;
    bool v0 = j0 < e0, v1 = j1 < e1;
    uint4 r0 = make_uint4(0u, 0u, 0u, 0u);
    uint4 r1 = make_uint4(0u, 0u, 0u, 0u);
    if (v0) {
      int u = ssrc[j0];
      r0 = *(const uint4*)(h + (size_t)u * DIM + dp);
    }
    if (v1) {
      int u = ssrc[j1];
      r1 = *(const uint4*)(h + (size_t)u * DIM + dp);
    }
    a0[0] += bf2f(r0.x & 0xffffu); a0[1] += bf2f(r0.x >> 16);
    a0[2] += bf2f(r0.y & 0xffffu); a0[3] += bf2f(r0.y >> 16);
    a0[4] += bf2f(r0.z & 0xffffu); a0[5] += bf2f(r0.z >> 16);
    a0[6] += bf2f(r0.w & 0xffffu); a0[7] += bf2f(r0.w >> 16);
    a1[0] += bf2f(r1.x & 0xffffu); a1[1] += bf2f(r1.x >> 16);
    a1[2] += bf2f(r1.y & 0xffffu); a1[3] += bf2f(r1.y >> 16);
    a1[4] += bf2f(r1.z & 0xffffu); a1[5] += bf2f(r1.z >> 16);
    a1[6] += bf2f(r1.w & 0xffffu); a1[7] += bf2f(r1.w >> 16);
  }

  #pragma unroll
  for (int i = 0; i < 8; ++i) {
    a0[i] += __shfl_xor(a0[i], 8);
    a0[i] += __shfl_xor(a0[i], 16);
    a0[i] += __shfl_xor(a0[i], 32);
    a1[i] += __shfl_xor(a1[i], 8);
    a1[i] += __shfl_xor(a1[i], 16);
    a1[i] += __shfl_xor(a1[i], 32);
  }
  if (sub == 0) {
    uint4 o0, o1;
    o0.x = pack2(a0[0], a0[1]); o0.y = pack2(a0[2], a0[3]);
    o0.z = pack2(a0[4], a0[5]); o0.w = pack2(a0[6], a0[7]);
    o1.x = pack2(a1[0], a1[1]); o1.y = pack2(a1[2], a1[3]);
    o1.z = pack2(a1[4], a1[5]); o1.w = pack2(a1[6], a1[7]);
    *(uint4*)(zb + (size_t)n0 * DIM + dp) = o0;
    *(uint4*)(zb + (size_t)n1 * DIM + dp) = o1;
  }
}

// ---------------- MFMA MLP: pre-transposed bf16 weights, BN folded ----------------

__global__ __launch_bounds__(256) void mlp_kernel(const ushort_t* __restrict__ zb,
                                                  ushort_t* __restrict__ hout,
                                                  const ushort_t* __restrict__ W1bT,
                                                  const float* __restrict__ b1p,
                                                  const ushort_t* __restrict__ W2bT,
                                                  const float* __restrict__ b2) {
  __shared__ ushort_t zs[128 * WSTR];
  __shared__ ushort_t wt1[64 * WSTR];
  __shared__ ushort_t wt2[64 * WSTR];

  const int t = threadIdx.x;
  const int base = blockIdx.x * 128;

  #pragma unroll
  for (int i = 0; i < 4; ++i) {
    int f = i * 256 + t;
    int row = f >> 3, seg = (f & 7) << 3;
    int gn = base + row;
    if (gn >= N_NODES) gn = N_NODES - 1;
    *(uint4*)(zs + row * WSTR + seg) = *(const uint4*)(zb + (size_t)gn * DIM + seg);
  }
  #pragma unroll
  for (int i = 0; i < 2; ++i) {
    int f = i * 256 + t;                 // 512 uint4 slots per matrix
    int n = f >> 3, kseg = (f & 7) << 3;
    *(uint4*)(wt1 + n * WSTR + kseg) = *(const uint4*)(W1bT + n * 64 + kseg);
    *(uint4*)(wt2 + n * WSTR + kseg) = *(const uint4*)(W2bT + n * 64 + kseg);
  }
  __syncthreads();

  const int lane = t & 63;
  const int w = t >> 6;
  const int lr = lane & 15;
  const int kc = lane >> 4;

  float o_[4], bb_[4];
  #pragma unroll
  for (int nt = 0; nt < 4; ++nt) {
    int od = nt * 16 + lr;
    o_[nt] = b1p[od];
    bb_[nt] = b2[od];
  }

  float4v acc[2][4];
  #pragma unroll
  for (int mt = 0; mt < 2; ++mt)
    #pragma unroll
    for (int nt = 0; nt < 4; ++nt)
      acc[mt][nt] = (float4v){0.f, 0.f, 0.f, 0.f};

  #pragma unroll
  for (int k0 = 0; k0 < 2; ++k0) {
    short8v bfr[4];
    #pragma unroll
    for (int nt = 0; nt < 4; ++nt)
      bfr[nt] = *(short8v*)(wt1 + (nt * 16 + lr) * WSTR + k0 * 32 + kc * 8);
    #pragma unroll
    for (int mt = 0; mt < 2; ++mt) {
      short8v afr = *(short8v*)(zs + ((w * 2 + mt) * 16 + lr) * WSTR + k0 * 32 + kc * 8);
      #pragma unroll
      for (int nt = 0; nt < 4; ++nt)
        acc[mt][nt] = __builtin_amdgcn_mfma_f32_16x16x32_bf16(afr, bfr[nt], acc[mt][nt], 0, 0, 0);
    }
  }

  #pragma unroll
  for (int mt = 0; mt < 2; ++mt)
    #pragma unroll
    for (int nt = 0; nt < 4; ++nt)
      #pragma unroll
      for (int r = 0; r < 4; ++r) {
        float v = acc[mt][nt][r] + o_[nt];
        v = v > 0.f ? v : 0.f;
        int node = (w * 2 + mt) * 16 + kc * 4 + r;
        zs[node * WSTR + nt * 16 + lr] = f2bf(v);
      }

  #pragma unroll
  for (int mt = 0; mt < 2; ++mt)
    #pragma unroll
    for (int nt = 0; nt < 4; ++nt)
      acc[mt][nt] = (float4v){0.f, 0.f, 0.f, 0.f};

  #pragma unroll
  for (int k0 = 0; k0 < 2; ++k0) {
    short8v bfr[4];
    #pragma unroll
    for (int nt = 0; nt < 4; ++nt)
      bfr[nt] = *(short8v*)(wt2 + (nt * 16 + lr) * WSTR + k0 * 32 + kc * 8);
    #pragma unroll
    for (int mt = 0; mt < 2; ++mt) {
      short8v afr = *(short8v*)(zs + ((w * 2 + mt) * 16 + lr) * WSTR + k0 * 32 + kc * 8);
      #pragma unroll
      for (int nt = 0; nt < 4; ++nt)
        acc[mt][nt] = __builtin_amdgcn_mfma_f32_16x16x32_bf16(afr, bfr[nt], acc[mt][nt], 0, 0, 0);
    }
  }

  #pragma unroll
  for (int mt = 0; mt < 2; ++mt)
    #pragma unroll
    for (int nt = 0; nt < 4; ++nt)
      #pragma unroll
      for (int r = 0; r < 4; ++r) {
        float v = acc[mt][nt][r] + bb_[nt];
        v = v > 0.f ? v : 0.f;
        int node = (w * 2 + mt) * 16 + kc * 4 + r;
        zs[node * WSTR + nt * 16 + lr] = f2bf(v);
      }
  __syncthreads();

  #pragma unroll
  for (int i = 0; i < 4; ++i) {
    int f = i * 256 + t;
    int row = f >> 3, seg = (f & 7) << 3;
    int gn = base + row;
    if (gn < N_NODES)
      *(uint4*)(hout + (size_t)gn * DIM + seg) = *(const uint4*)(zs + row * WSTR + seg);
  }
}

// ---------------- pool: partial sums (batch sorted) + tiny head ----------------

__global__ __launch_bounds__(256) void pool_partial_kernel(const ushort_t* __restrict__ h,
                                                           const int* __restrict__ batch,
                                                           float* __restrict__ pooled) {
  int r0 = blockIdx.x * POOL_CH;
  int rend = min(r0 + POOL_CH, N_NODES);
  int w = threadIdx.x >> 6, d = threadIdx.x & 63;
  float acc = 0.f;
  int curg = -1;
  for (int i = r0 + w; i < rend; i += 4) {
    int g = batch[i];
    if (g != curg) {
      if (curg >= 0) atomicAdd(&pooled[curg * DIM + d], acc);
      acc = 0.f;
      curg = g;
    }
    acc += bf2f((uint_t)h[i * DIM + d]);
  }
  if (curg >= 0) atomicAdd(&pooled[curg * DIM + d], acc);
}

__global__ __launch_bounds__(256) void head_kernel(const float* __restrict__ pooled,
                                                   const float* __restrict__ lw,
                                                   const float* __restrict__ lb,
                                                   float* __restrict__ out) {
  int idx = blockIdx.x * 256 + threadIdx.x;
  if (idx >= N_GRAPHS * DIM) return;
  int g = idx >> 6, d = idx & 63;
  float o = lb[d];
  #pragma unroll 8
  for (int k = 0; k < 64; ++k) o = fmaf(pooled[g * 64 + k], lw[k * 64 + d], o);
  out[idx] = fmaxf(o, 0.f);
}

// ---------------- host ----------------

extern "C" void kernel_launch(void* const* d_in, const int* in_sizes, int n_in,
                              void* d_out, int out_size, void* d_ws, size_t ws_size,
                              hipStream_t stream) {
  const float* x      = (const float*)d_in[0];
  const int*   ei     = (const int*)d_in[1];
  const int*   srcp   = ei;
  const int*   dstp   = ei + N_EDGES;
  const int*   batch  = (const int*)d_in[2];
  const float* W1s    = (const float*)d_in[3];
  const float* b1s    = (const float*)d_in[4];
  const float* gammas = (const float*)d_in[5];
  const float* betas  = (const float*)d_in[6];
  const float* W2s    = (const float*)d_in[7];
  const float* b2s    = (const float*)d_in[8];
  const float* lin1_w = (const float*)d_in[9];
  const float* lin1_b = (const float*)d_in[10];

  char* p = (char*)d_ws;
  ushort_t* xb     = (ushort_t*)p; p += (size_t)N_NODES * DIM * 2;      // 12.8 MB
  ushort_t* h1     = (ushort_t*)p; p += (size_t)N_NODES * DIM * 2;      // 12.8 MB
  ushort_t* zbuf   = (ushort_t*)p; p += (size_t)N_NODES * DIM * 2;      // 12.8 MB
  uint_t*   gPairs = (uint_t*)p;   p += (size_t)NBUCKETS * BCAP * 4;    // 6.4 MB
  int*      ssrc   = (int*)p;      p += (size_t)N_EDGES * 4;            // 4.8 MB
  int*      rowptr = (int*)p;      p += 100352 * sizeof(int);
  int*      gCursor    = (int*)p;  p += 4096;
  int*      bucketBase = (int*)p;  p += 4096;
  ushort_t* W1bT   = (ushort_t*)p; p += N_LAYERS * 4096 * 2;
  ushort_t* W2bT   = (ushort_t*)p; p += N_LAYERS * 4096 * 2;
  float*    b1p    = (float*)p;    p += N_LAYERS * 64 * sizeof(float);
  float*    pooled = (float*)p;

  hipMemsetAsync(gCursor, 0, 1024 * sizeof(int), stream);
  hipMemsetAsync(pooled, 0, N_GRAPHS * DIM * sizeof(float), stream);
  conv_kernel<<<(N_NODES * DIM / 8 + 255) / 256, 256, 0, stream>>>(x, xb);
  wconv_kernel<<<(N_LAYERS * 4096 + 255) / 256, 256, 0, stream>>>(
      W1s, b1s, gammas, betas, W2s, W1bT, W2bT, b1p);

  const int BIN_BLOCKS = (N_EDGES + CHUNK - 1) / CHUNK;   // 147
  bin_kernel<<<BIN_BLOCKS, 256, 0, stream>>>(srcp, dstp, gCursor, gPairs);
  bscan_kernel<<<1, 1024, 0, stream>>>(gCursor, bucketBase);
  csort_kernel<<<NBUCKETS, 256, 0, stream>>>(gCursor, bucketBase, gPairs, rowptr, ssrc);

  const int AGG_BLOCKS = (N_NODES / 2 + 3) / 4;      // 12500 (pairs, 4 per block)
  const int MLP_BLOCKS = NBUCKETS;                   // 782

  const ushort_t* hin = xb;
  for (int l = 0; l < N_LAYERS; ++l) {
    ushort_t* hout = (l & 1) ? xb : h1;
    agg_kernel<<<AGG_BLOCKS, 256, 0, stream>>>(hin, rowptr, ssrc, zbuf);
    mlp_kernel<<<MLP_BLOCKS, 256, 0, stream>>>(zbuf, hout,
        W1bT + (size_t)l * 4096, b1p + (size_t)l * 64,
        W2bT + (size_t)l * 4096, b2s + (size_t)l * DIM);
    hin = hout;
  }

  pool_partial_kernel<<<POOL_BLOCKS, 256, 0, stream>>>(h1, batch, pooled);
  head_kernel<<<(N_GRAPHS * DIM + 255) / 256, 256, 0, stream>>>(pooled, lin1_w, lin1_b, (float*)d_out);
}

// Round 12
// 286.087 us; speedup vs baseline: 1.4222x; 1.0207x over previous
//
#include <hip/hip_runtime.h>

#define N_NODES 100000
#define N_EDGES 1200000
#define DIM 64
#define N_GRAPHS 128
#define N_LAYERS 5

#define NBUCKETS 782          // ceil(100000/128)
#define BCAP 2048             // per-bucket capacity (mean 1534, +13 sigma)
#define CHUNK 8192            // edges per bin block

#define POOL_CH 196
#define POOL_BLOCKS ((N_NODES + POOL_CH - 1) / POOL_CH)

#define WSTR 72               // bf16 LDS row stride

typedef unsigned short ushort_t;
typedef unsigned int uint_t;
typedef __attribute__((ext_vector_type(8))) short short8v;   // 8 bf16 = 4 VGPR
typedef __attribute__((ext_vector_type(4))) float float4v;

__device__ __forceinline__ float bf2f(uint_t s) {
  return __uint_as_float(s << 16);
}
__device__ __forceinline__ ushort_t f2bf(float f) {
  uint_t u = __float_as_uint(f);
  uint_t r = u + 0x7fffu + ((u >> 16) & 1u);   // RNE
  return (ushort_t)(r >> 16);
}
__device__ __forceinline__ uint_t pack2(float a, float b) {
  return (uint_t)f2bf(a) | ((uint_t)f2bf(b) << 16);
}

// ---------------- fp32 -> bf16 convert (x only, once) ----------------

__global__ __launch_bounds__(256) void conv_kernel(const float* __restrict__ x,
                                                   ushort_t* __restrict__ xb) {
  int i = blockIdx.x * 256 + threadIdx.x;
  int base = i * 8;
  if (base >= N_NODES * DIM) return;
  float4 a = *(const float4*)(x + base);
  float4 b = *(const float4*)(x + base + 4);
  uint4 o;
  o.x = pack2(a.x, a.y);
  o.y = pack2(a.z, a.w);
  o.z = pack2(b.x, b.y);
  o.w = pack2(b.z, b.w);
  *(uint4*)(xb + base) = o;
}

// ---------------- weight prep (once): transpose to bf16, fold BN into W1 ----------------

__global__ __launch_bounds__(256) void wconv_kernel(const float* __restrict__ W1s,
                                                    const float* __restrict__ b1s,
                                                    const float* __restrict__ gammas,
                                                    const float* __restrict__ betas,
                                                    const float* __restrict__ W2s,
                                                    ushort_t* __restrict__ W1bT,
                                                    ushort_t* __restrict__ W2bT,
                                                    float* __restrict__ b1p) {
  int idx = blockIdx.x * 256 + threadIdx.x;
  if (idx >= N_LAYERS * 4096) return;
  int l = idx >> 12, rem = idx & 4095;
  int n = rem >> 6, k = rem & 63;
  const float BNR = 0.99999500003749971893f;   // 1/sqrt(1+1e-5)
  float sc = gammas[l * 64 + n] * BNR;
  W1bT[(size_t)l * 4096 + n * 64 + k] = f2bf(W1s[(size_t)l * 4096 + k * 64 + n] * sc);
  W2bT[(size_t)l * 4096 + n * 64 + k] = f2bf(W2s[(size_t)l * 4096 + k * 64 + n]);
  if (k == 0) b1p[l * 64 + n] = fmaf(b1s[l * 64 + n], sc, betas[l * 64 + n]);
}

// ---------------- CSR build stage 1: LDS multisplit into 782 buckets ----------------

__global__ __launch_bounds__(256) void bin_kernel(const int* __restrict__ src,
                                                  const int* __restrict__ dst,
                                                  int* __restrict__ gCursor,
                                                  uint_t* __restrict__ gPairs) {
  __shared__ int hist[NBUCKETS];
  __shared__ int lstart[NBUCKETS];
  __shared__ int lcur[NBUCKETS];
  __shared__ int gbase[NBUCKETS];
  __shared__ uint_t pairbuf[CHUNK];
  __shared__ ushort_t bidbuf[CHUNK];
  __shared__ int wsum[4];

  const int t = threadIdx.x;
  const int e0 = blockIdx.x * CHUNK;
  const int ecnt = min(CHUNK, N_EDGES - e0);

  for (int i = t; i < NBUCKETS; i += 256) hist[i] = 0;
  __syncthreads();

  for (int i = t; i < ecnt; i += 256) {
    int d = dst[e0 + i];
    atomicAdd(&hist[d >> 7], 1);
  }
  __syncthreads();

  const int base4 = t * 4;
  int h0 = 0, h1 = 0, h2 = 0, h3 = 0;
  if (base4 + 0 < NBUCKETS) h0 = hist[base4 + 0];
  if (base4 + 1 < NBUCKETS) h1 = hist[base4 + 1];
  if (base4 + 2 < NBUCKETS) h2 = hist[base4 + 2];
  if (base4 + 3 < NBUCKETS) h3 = hist[base4 + 3];
  int tsum = h0 + h1 + h2 + h3;
  int lane = t & 63, wid = t >> 6;
  int inc = tsum;
  #pragma unroll
  for (int off = 1; off < 64; off <<= 1) {
    int v = __shfl_up(inc, off);
    if (lane >= off) inc += v;
  }
  if (lane == 63) wsum[wid] = inc;
  __syncthreads();
  int wadd = 0;
  for (int w = 0; w < wid; ++w) wadd += wsum[w];
  int ex = wadd + inc - tsum;
  if (base4 + 0 < NBUCKETS) { lstart[base4 + 0] = ex; lcur[base4 + 0] = ex; } ex += h0;
  if (base4 + 1 < NBUCKETS) { lstart[base4 + 1] = ex; lcur[base4 + 1] = ex; } ex += h1;
  if (base4 + 2 < NBUCKETS) { lstart[base4 + 2] = ex; lcur[base4 + 2] = ex; } ex += h2;
  if (base4 + 3 < NBUCKETS) { lstart[base4 + 3] = ex; lcur[base4 + 3] = ex; }
  __syncthreads();

  for (int i = t; i < ecnt; i += 256) {
    int s = src[e0 + i];
    int d = dst[e0 + i];
    int b = d >> 7;
    int p = atomicAdd(&lcur[b], 1);
    pairbuf[p] = (uint_t)s | ((uint_t)(d & 127) << 17);
    bidbuf[p] = (ushort_t)b;
  }
  __syncthreads();

  for (int b = t; b < NBUCKETS; b += 256) {
    int cnt = lcur[b] - lstart[b];
    gbase[b] = cnt ? atomicAdd(&gCursor[b], cnt) : 0;
  }
  __syncthreads();

  for (int i = t; i < ecnt; i += 256) {
    int b = bidbuf[i];
    int pos = gbase[b] + (i - lstart[b]);
    if (pos < BCAP) gPairs[b * BCAP + pos] = pairbuf[i];
  }
}

__global__ __launch_bounds__(1024) void bscan_kernel(const int* __restrict__ gCursor,
                                                     int* __restrict__ bucketBase) {
  __shared__ int sm[1024];
  int t = threadIdx.x;
  int v = (t < NBUCKETS) ? min(gCursor[t], BCAP) : 0;
  sm[t] = v;
  __syncthreads();
  for (int off = 1; off < 1024; off <<= 1) {
    int x = (t >= off) ? sm[t - off] : 0;
    __syncthreads();
    sm[t] += x;
    __syncthreads();
  }
  bucketBase[t] = sm[t] - v;
  if (t == NBUCKETS - 1) bucketBase[NBUCKETS] = sm[t];
}

// ---------------- stage 2: per-bucket counting sort by (dstLocal, srcCoarse) ----------------

__global__ __launch_bounds__(256) void csort_kernel(const int* __restrict__ gCursor,
                                                    const int* __restrict__ bucketBase,
                                                    const uint_t* __restrict__ gPairs,
                                                    int* __restrict__ rowptr,
                                                    int* __restrict__ ssrc) {
  __shared__ uint_t vals[BCAP];
  __shared__ int ssl[BCAP];
  __shared__ int hist[1024];
  __shared__ int cur[1024];
  __shared__ int wsum[4];

  const int b = blockIdx.x, t = threadIdx.x;
  const int cnt = min(gCursor[b], BCAP);
  const int base = bucketBase[b];
  const int n0 = b << 7;
  const int nn = min(128, N_NODES - n0);

  for (int i = t; i < 1024; i += 256) hist[i] = 0;
  __syncthreads();
  for (int i = t; i < cnt; i += 256) {
    uint_t v = gPairs[b * BCAP + i];
    vals[i] = v;
    int bin = (int)((v >> 17) & 127u) * 8 + (int)((v & 0x1FFFFu) >> 14);
    atomicAdd(&hist[bin], 1);
  }
  __syncthreads();

  const int b4 = t * 4;
  int h0 = hist[b4], h1 = hist[b4 + 1], h2 = hist[b4 + 2], h3 = hist[b4 + 3];
  int tsum = h0 + h1 + h2 + h3;
  int lane = t & 63, wid = t >> 6;
  int inc = tsum;
  #pragma unroll
  for (int off = 1; off < 64; off <<= 1) {
    int v = __shfl_up(inc, off);
    if (lane >= off) inc += v;
  }
  if (lane == 63) wsum[wid] = inc;
  __syncthreads();
  int wadd = 0;
  for (int w = 0; w < wid; ++w) wadd += wsum[w];
  int ex = wadd + inc - tsum;
  #pragma unroll
  for (int q = 0; q < 4; ++q) {
    int bin = b4 + q;
    cur[bin] = ex;
    if ((bin & 7) == 0) {
      int dl = bin >> 3;
      if (dl < nn) rowptr[n0 + dl] = base + ex;
    }
    ex += hist[bin];
  }
  if (b == NBUCKETS - 1 && t == 0) rowptr[N_NODES] = base + cnt;
  __syncthreads();

  for (int i = t; i < cnt; i += 256) {
    uint_t v = vals[i];
    int bin = (int)((v >> 17) & 127u) * 8 + (int)((v & 0x1FFFFu) >> 14);
    int p = atomicAdd(&cur[bin], 1);
    ssl[p] = (int)(v & 0x1FFFFu);
  }
  __syncthreads();
  for (int i = t; i < cnt; i += 256) ssrc[base + i] = ssl[i];
}

// ---------------- aggregation: 2 nodes per wave, depth-2 software pipeline ----------------
// lane l: edge slot l>>3 (0..7), dims ((l&7)*8) as uint4. Iteration it+1's loads
// are issued BEFORE iteration it's rows are accumulated -> up to 4 gathers in flight.

#define ACC8(A, R)                                                    \
  A[0] += bf2f(R.x & 0xffffu); A[1] += bf2f(R.x >> 16);               \
  A[2] += bf2f(R.y & 0xffffu); A[3] += bf2f(R.y >> 16);               \
  A[4] += bf2f(R.z & 0xffffu); A[5] += bf2f(R.z >> 16);               \
  A[6] += bf2f(R.w & 0xffffu); A[7] += bf2f(R.w >> 16);

__global__ __launch_bounds__(256) void agg_kernel(const ushort_t* __restrict__ h,
                                                  const int* __restrict__ rowptr,
                                                  const int* __restrict__ ssrc,
                                                  ushort_t* __restrict__ zb) {
  int pair = blockIdx.x * 4 + (threadIdx.x >> 6);
  int l = threadIdx.x & 63;
  int n0 = pair * 2;
  if (n0 >= N_NODES) return;
  int n1 = n0 + 1;                      // N even -> always < N_NODES
  int sub = l >> 3;
  int dp = (l & 7) << 3;

  float a0[8], a1[8];
  #pragma unroll
  for (int i = 0; i < 8; ++i) { a0[i] = 0.f; a1[i] = 0.f; }

  int s0 = rowptr[n0], e0 = rowptr[n0 + 1];
  int s1 = e0,         e1 = rowptr[n1 + 1];   // rowptr contiguous

  if (sub == 0) {
    uint4 r = *(const uint4*)(h + (size_t)n0 * DIM + dp);
    uint4 q = *(const uint4*)(h + (size_t)n1 * DIM + dp);
    ACC8(a0, r);
    ACC8(a1, q);
  }

  const uint4 zz = make_uint4(0u, 0u, 0u, 0u);
  int j0 = s0 + sub, j1 = s1 + sub;
  uint4 r0 = zz, r1 = zz;
  if (j0 < e0) r0 = *(const uint4*)(h + (size_t)ssrc[j0] * DIM + dp);
  if (j1 < e1) r1 = *(const uint4*)(h + (size_t)ssrc[j1] * DIM + dp);

  int iters = (max(e0 - s0, e1 - s1) + 7) >> 3;
  for (int it = 1; it < iters; ++it) {
    int nj0 = j0 + 8, nj1 = j1 + 8;
    uint4 p0 = zz, p1 = zz;
    if (nj0 < e0) p0 = *(const uint4*)(h + (size_t)ssrc[nj0] * DIM + dp);
    if (nj1 < e1) p1 = *(const uint4*)(h + (size_t)ssrc[nj1] * DIM + dp);
    ACC8(a0, r0);
    ACC8(a1, r1);
    r0 = p0; r1 = p1;
    j0 = nj0; j1 = nj1;
  }
  ACC8(a0, r0);
  ACC8(a1, r1);

  #pragma unroll
  for (int i = 0; i < 8; ++i) {
    a0[i] += __shfl_xor(a0[i], 8);
    a0[i] += __shfl_xor(a0[i], 16);
    a0[i] += __shfl_xor(a0[i], 32);
    a1[i] += __shfl_xor(a1[i], 8);
    a1[i] += __shfl_xor(a1[i], 16);
    a1[i] += __shfl_xor(a1[i], 32);
  }
  if (sub == 0) {
    uint4 o0, o1;
    o0.x = pack2(a0[0], a0[1]); o0.y = pack2(a0[2], a0[3]);
    o0.z = pack2(a0[4], a0[5]); o0.w = pack2(a0[6], a0[7]);
    o1.x = pack2(a1[0], a1[1]); o1.y = pack2(a1[2], a1[3]);
    o1.z = pack2(a1[4], a1[5]); o1.w = pack2(a1[6], a1[7]);
    *(uint4*)(zb + (size_t)n0 * DIM + dp) = o0;
    *(uint4*)(zb + (size_t)n1 * DIM + dp) = o1;
  }
}

// ---------------- MFMA MLP: pre-transposed bf16 weights, BN folded ----------------

__global__ __launch_bounds__(256) void mlp_kernel(const ushort_t* __restrict__ zb,
                                                  ushort_t* __restrict__ hout,
                                                  const ushort_t* __restrict__ W1bT,
                                                  const float* __restrict__ b1p,
                                                  const ushort_t* __restrict__ W2bT,
                                                  const float* __restrict__ b2) {
  __shared__ ushort_t zs[128 * WSTR];
  __shared__ ushort_t wt1[64 * WSTR];
  __shared__ ushort_t wt2[64 * WSTR];

  const int t = threadIdx.x;
  const int base = blockIdx.x * 128;

  #pragma unroll
  for (int i = 0; i < 4; ++i) {
    int f = i * 256 + t;
    int row = f >> 3, seg = (f & 7) << 3;
    int gn = base + row;
    if (gn >= N_NODES) gn = N_NODES - 1;
    *(uint4*)(zs + row * WSTR + seg) = *(const uint4*)(zb + (size_t)gn * DIM + seg);
  }
  #pragma unroll
  for (int i = 0; i < 2; ++i) {
    int f = i * 256 + t;                 // 512 uint4 slots per matrix
    int n = f >> 3, kseg = (f & 7) << 3;
    *(uint4*)(wt1 + n * WSTR + kseg) = *(const uint4*)(W1bT + n * 64 + kseg);
    *(uint4*)(wt2 + n * WSTR + kseg) = *(const uint4*)(W2bT + n * 64 + kseg);
  }
  __syncthreads();

  const int lane = t & 63;
  const int w = t >> 6;
  const int lr = lane & 15;
  const int kc = lane >> 4;

  float o_[4], bb_[4];
  #pragma unroll
  for (int nt = 0; nt < 4; ++nt) {
    int od = nt * 16 + lr;
    o_[nt] = b1p[od];
    bb_[nt] = b2[od];
  }

  float4v acc[2][4];
  #pragma unroll
  for (int mt = 0; mt < 2; ++mt)
    #pragma unroll
    for (int nt = 0; nt < 4; ++nt)
      acc[mt][nt] = (float4v){0.f, 0.f, 0.f, 0.f};

  #pragma unroll
  for (int k0 = 0; k0 < 2; ++k0) {
    short8v bfr[4];
    #pragma unroll
    for (int nt = 0; nt < 4; ++nt)
      bfr[nt] = *(short8v*)(wt1 + (nt * 16 + lr) * WSTR + k0 * 32 + kc * 8);
    #pragma unroll
    for (int mt = 0; mt < 2; ++mt) {
      short8v afr = *(short8v*)(zs + ((w * 2 + mt) * 16 + lr) * WSTR + k0 * 32 + kc * 8);
      #pragma unroll
      for (int nt = 0; nt < 4; ++nt)
        acc[mt][nt] = __builtin_amdgcn_mfma_f32_16x16x32_bf16(afr, bfr[nt], acc[mt][nt], 0, 0, 0);
    }
  }

  #pragma unroll
  for (int mt = 0; mt < 2; ++mt)
    #pragma unroll
    for (int nt = 0; nt < 4; ++nt)
      #pragma unroll
      for (int r = 0; r < 4; ++r) {
        float v = acc[mt][nt][r] + o_[nt];
        v = v > 0.f ? v : 0.f;
        int node = (w * 2 + mt) * 16 + kc * 4 + r;
        zs[node * WSTR + nt * 16 + lr] = f2bf(v);
      }

  #pragma unroll
  for (int mt = 0; mt < 2; ++mt)
    #pragma unroll
    for (int nt = 0; nt < 4; ++nt)
      acc[mt][nt] = (float4v){0.f, 0.f, 0.f, 0.f};

  #pragma unroll
  for (int k0 = 0; k0 < 2; ++k0) {
    short8v bfr[4];
    #pragma unroll
    for (int nt = 0; nt < 4; ++nt)
      bfr[nt] = *(short8v*)(wt2 + (nt * 16 + lr) * WSTR + k0 * 32 + kc * 8);
    #pragma unroll
    for (int mt = 0; mt < 2; ++mt) {
      short8v afr = *(short8v*)(zs + ((w * 2 + mt) * 16 + lr) * WSTR + k0 * 32 + kc * 8);
      #pragma unroll
      for (int nt = 0; nt < 4; ++nt)
        acc[mt][nt] = __builtin_amdgcn_mfma_f32_16x16x32_bf16(afr, bfr[nt], acc[mt][nt], 0, 0, 0);
    }
  }

  #pragma unroll
  for (int mt = 0; mt < 2; ++mt)
    #pragma unroll
    for (int nt = 0; nt < 4; ++nt)
      #pragma unroll
      for (int r = 0; r < 4; ++r) {
        float v = acc[mt][nt][r] + bb_[nt];
        v = v > 0.f ? v : 0.f;
        int node = (w * 2 + mt) * 16 + kc * 4 + r;
        zs[node * WSTR + nt * 16 + lr] = f2bf(v);
      }
  __syncthreads();

  #pragma unroll
  for (int i = 0; i < 4; ++i) {
    int f = i * 256 + t;
    int row = f >> 3, seg = (f & 7) << 3;
    int gn = base + row;
    if (gn < N_NODES)
      *(uint4*)(hout + (size_t)gn * DIM + seg) = *(const uint4*)(zs + row * WSTR + seg);
  }
}

// ---------------- pool: partial sums (batch sorted) + tiny head ----------------

__global__ __launch_bounds__(256) void pool_partial_kernel(const ushort_t* __restrict__ h,
                                                           const int* __restrict__ batch,
                                                           float* __restrict__ pooled) {
  int r0 = blockIdx.x * POOL_CH;
  int rend = min(r0 + POOL_CH, N_NODES);
  int w = threadIdx.x >> 6, d = threadIdx.x & 63;
  float acc = 0.f;
  int curg = -1;
  for (int i = r0 + w; i < rend; i += 4) {
    int g = batch[i];
    if (g != curg) {
      if (curg >= 0) atomicAdd(&pooled[curg * DIM + d], acc);
      acc = 0.f;
      curg = g;
    }
    acc += bf2f((uint_t)h[i * DIM + d]);
  }
  if (curg >= 0) atomicAdd(&pooled[curg * DIM + d], acc);
}

__global__ __launch_bounds__(256) void head_kernel(const float* __restrict__ pooled,
                                                   const float* __restrict__ lw,
                                                   const float* __restrict__ lb,
                                                   float* __restrict__ out) {
  int idx = blockIdx.x * 256 + threadIdx.x;
  if (idx >= N_GRAPHS * DIM) return;
  int g = idx >> 6, d = idx & 63;
  float o = lb[d];
  #pragma unroll 8
  for (int k = 0; k < 64; ++k) o = fmaf(pooled[g * 64 + k], lw[k * 64 + d], o);
  out[idx] = fmaxf(o, 0.f);
}

// ---------------- host ----------------

extern "C" void kernel_launch(void* const* d_in, const int* in_sizes, int n_in,
                              void* d_out, int out_size, void* d_ws, size_t ws_size,
                              hipStream_t stream) {
  const float* x      = (const float*)d_in[0];
  const int*   ei     = (const int*)d_in[1];
  const int*   srcp   = ei;
  const int*   dstp   = ei + N_EDGES;
  const int*   batch  = (const int*)d_in[2];
  const float* W1s    = (const float*)d_in[3];
  const float* b1s    = (const float*)d_in[4];
  const float* gammas = (const float*)d_in[5];
  const float* betas  = (const float*)d_in[6];
  const float* W2s    = (const float*)d_in[7];
  const float* b2s    = (const float*)d_in[8];
  const float* lin1_w = (const float*)d_in[9];
  const float* lin1_b = (const float*)d_in[10];

  char* p = (char*)d_ws;
  ushort_t* xb     = (ushort_t*)p; p += (size_t)N_NODES * DIM * 2;      // 12.8 MB
  ushort_t* h1     = (ushort_t*)p; p += (size_t)N_NODES * DIM * 2;      // 12.8 MB
  ushort_t* zbuf   = (ushort_t*)p; p += (size_t)N_NODES * DIM * 2;      // 12.8 MB
  uint_t*   gPairs = (uint_t*)p;   p += (size_t)NBUCKETS * BCAP * 4;    // 6.4 MB
  int*      ssrc   = (int*)p;      p += (size_t)N_EDGES * 4;            // 4.8 MB
  int*      rowptr = (int*)p;      p += 100352 * sizeof(int);
  int*      gCursor    = (int*)p;  p += 4096;
  int*      bucketBase = (int*)p;  p += 4096;
  ushort_t* W1bT   = (ushort_t*)p; p += N_LAYERS * 4096 * 2;
  ushort_t* W2bT   = (ushort_t*)p; p += N_LAYERS * 4096 * 2;
  float*    b1p    = (float*)p;    p += N_LAYERS * 64 * sizeof(float);
  float*    pooled = (float*)p;

  hipMemsetAsync(gCursor, 0, 1024 * sizeof(int), stream);
  hipMemsetAsync(pooled, 0, N_GRAPHS * DIM * sizeof(float), stream);
  conv_kernel<<<(N_NODES * DIM / 8 + 255) / 256, 256, 0, stream>>>(x, xb);
  wconv_kernel<<<(N_LAYERS * 4096 + 255) / 256, 256, 0, stream>>>(
      W1s, b1s, gammas, betas, W2s, W1bT, W2bT, b1p);

  const int BIN_BLOCKS = (N_EDGES + CHUNK - 1) / CHUNK;   // 147
  bin_kernel<<<BIN_BLOCKS, 256, 0, stream>>>(srcp, dstp, gCursor, gPairs);
  bscan_kernel<<<1, 1024, 0, stream>>>(gCursor, bucketBase);
  csort_kernel<<<NBUCKETS, 256, 0, stream>>>(gCursor, bucketBase, gPairs, rowptr, ssrc);

  const int AGG_BLOCKS = (N_NODES / 2 + 3) / 4;      // 12500 (pairs, 4 per block)
  const int MLP_BLOCKS = NBUCKETS;                   // 782

  const ushort_t* hin = xb;
  for (int l = 0; l < N_LAYERS; ++l) {
    ushort_t* hout = (l & 1) ? xb : h1;
    agg_kernel<<<AGG_BLOCKS, 256, 0, stream>>>(hin, rowptr, ssrc, zbuf);
    mlp_kernel<<<MLP_BLOCKS, 256, 0, stream>>>(zbuf, hout,
        W1bT + (size_t)l * 4096, b1p + (size_t)l * 64,
        W2bT + (size_t)l * 4096, b2s + (size_t)l * DIM);
    hin = hout;
  }

  pool_partial_kernel<<<POOL_BLOCKS, 256, 0, stream>>>(h1, batch, pooled);
  head_kernel<<<(N_GRAPHS * DIM + 255) / 256, 256, 0, stream>>>(pooled, lin1_w, lin1_b, (float*)d_out);
}

// Round 13
// 284.544 us; speedup vs baseline: 1.4299x; 1.0054x over previous
//
#include <hip/hip_runtime.h>

#define N_NODES 100000
#define N_EDGES 1200000
#define DIM 64
#define N_GRAPHS 128
#define N_LAYERS 5

#define NBUCKETS 782          // ceil(100000/128)
#define BCAP 2048             // per-bucket capacity (mean 1534, +13 sigma)
#define CHUNK 8192            // edges per bin block

#define POOL_CH 196
#define POOL_BLOCKS ((N_NODES + POOL_CH - 1) / POOL_CH)

#define WSTR 72               // bf16 LDS row stride

#define CONV_BLOCKS 3125      // N_NODES*DIM/8/256

typedef unsigned short ushort_t;
typedef unsigned int uint_t;
typedef __attribute__((ext_vector_type(8))) short short8v;   // 8 bf16 = 4 VGPR
typedef __attribute__((ext_vector_type(4))) float float4v;
typedef __attribute__((ext_vector_type(2))) float float2v;

__device__ __forceinline__ float bf2f(uint_t s) {
  return __uint_as_float(s << 16);
}
__device__ __forceinline__ ushort_t f2bf(float f) {
  uint_t u = __float_as_uint(f);
  uint_t r = u + 0x7fffu + ((u >> 16) & 1u);   // RNE
  return (ushort_t)(r >> 16);
}
__device__ __forceinline__ uint_t pack2(float a, float b) {
  return (uint_t)f2bf(a) | ((uint_t)f2bf(b) << 16);
}
// {lo, hi} bf16 pair -> packed f32 pair (hi needs only an AND: bf16<<16 is f32)
__device__ __forceinline__ float2v bfpair(uint_t u) {
  return (float2v){__uint_as_float(u << 16), __uint_as_float(u & 0xffff0000u)};
}

// ---------------- prep: x->bf16 convert + weight transpose/fold (one launch) ----------------

__global__ __launch_bounds__(256) void prep_kernel(const float* __restrict__ x,
                                                   ushort_t* __restrict__ xb,
                                                   const float* __restrict__ W1s,
                                                   const float* __restrict__ b1s,
                                                   const float* __restrict__ gammas,
                                                   const float* __restrict__ betas,
                                                   const float* __restrict__ W2s,
                                                   ushort_t* __restrict__ W1bT,
                                                   ushort_t* __restrict__ W2bT,
                                                   float* __restrict__ b1p) {
  int bid = blockIdx.x;
  if (bid < CONV_BLOCKS) {
    int base = (bid * 256 + threadIdx.x) * 8;
    float4 a = *(const float4*)(x + base);
    float4 b = *(const float4*)(x + base + 4);
    uint4 o;
    o.x = pack2(a.x, a.y);
    o.y = pack2(a.z, a.w);
    o.z = pack2(b.x, b.y);
    o.w = pack2(b.z, b.w);
    *(uint4*)(xb + base) = o;
  } else {
    int idx = (bid - CONV_BLOCKS) * 256 + threadIdx.x;
    if (idx >= N_LAYERS * 4096) return;
    int l = idx >> 12, rem = idx & 4095;
    int n = rem >> 6, k = rem & 63;
    const float BNR = 0.99999500003749971893f;   // 1/sqrt(1+1e-5)
    float sc = gammas[l * 64 + n] * BNR;
    W1bT[(size_t)l * 4096 + n * 64 + k] = f2bf(W1s[(size_t)l * 4096 + k * 64 + n] * sc);
    W2bT[(size_t)l * 4096 + n * 64 + k] = f2bf(W2s[(size_t)l * 4096 + k * 64 + n]);
    if (k == 0) b1p[l * 64 + n] = fmaf(b1s[l * 64 + n], sc, betas[l * 64 + n]);
  }
}

// ---------------- CSR build stage 1: LDS multisplit into 782 buckets ----------------

__global__ __launch_bounds__(256) void bin_kernel(const int* __restrict__ src,
                                                  const int* __restrict__ dst,
                                                  int* __restrict__ gCursor,
                                                  uint_t* __restrict__ gPairs) {
  __shared__ int hist[NBUCKETS];
  __shared__ int lstart[NBUCKETS];
  __shared__ int lcur[NBUCKETS];
  __shared__ int gbase[NBUCKETS];
  __shared__ uint_t pairbuf[CHUNK];
  __shared__ ushort_t bidbuf[CHUNK];
  __shared__ int wsum[4];

  const int t = threadIdx.x;
  const int e0 = blockIdx.x * CHUNK;
  const int ecnt = min(CHUNK, N_EDGES - e0);

  for (int i = t; i < NBUCKETS; i += 256) hist[i] = 0;
  __syncthreads();

  for (int i = t; i < ecnt; i += 256) {
    int d = dst[e0 + i];
    atomicAdd(&hist[d >> 7], 1);
  }
  __syncthreads();

  const int base4 = t * 4;
  int h0 = 0, h1 = 0, h2 = 0, h3 = 0;
  if (base4 + 0 < NBUCKETS) h0 = hist[base4 + 0];
  if (base4 + 1 < NBUCKETS) h1 = hist[base4 + 1];
  if (base4 + 2 < NBUCKETS) h2 = hist[base4 + 2];
  if (base4 + 3 < NBUCKETS) h3 = hist[base4 + 3];
  int tsum = h0 + h1 + h2 + h3;
  int lane = t & 63, wid = t >> 6;
  int inc = tsum;
  #pragma unroll
  for (int off = 1; off < 64; off <<= 1) {
    int v = __shfl_up(inc, off);
    if (lane >= off) inc += v;
  }
  if (lane == 63) wsum[wid] = inc;
  __syncthreads();
  int wadd = 0;
  for (int w = 0; w < wid; ++w) wadd += wsum[w];
  int ex = wadd + inc - tsum;
  if (base4 + 0 < NBUCKETS) { lstart[base4 + 0] = ex; lcur[base4 + 0] = ex; } ex += h0;
  if (base4 + 1 < NBUCKETS) { lstart[base4 + 1] = ex; lcur[base4 + 1] = ex; } ex += h1;
  if (base4 + 2 < NBUCKETS) { lstart[base4 + 2] = ex; lcur[base4 + 2] = ex; } ex += h2;
  if (base4 + 3 < NBUCKETS) { lstart[base4 + 3] = ex; lcur[base4 + 3] = ex; }
  __syncthreads();

  for (int i = t; i < ecnt; i += 256) {
    int s = src[e0 + i];
    int d = dst[e0 + i];
    int b = d >> 7;
    int p = atomicAdd(&lcur[b], 1);
    pairbuf[p] = (uint_t)s | ((uint_t)(d & 127) << 17);
    bidbuf[p] = (ushort_t)b;
  }
  __syncthreads();

  for (int b = t; b < NBUCKETS; b += 256) {
    int cnt = lcur[b] - lstart[b];
    gbase[b] = cnt ? atomicAdd(&gCursor[b], cnt) : 0;
  }
  __syncthreads();

  for (int i = t; i < ecnt; i += 256) {
    int b = bidbuf[i];
    int pos = gbase[b] + (i - lstart[b]);
    if (pos < BCAP) gPairs[b * BCAP + pos] = pairbuf[i];
  }
}

__global__ __launch_bounds__(1024) void bscan_kernel(const int* __restrict__ gCursor,
                                                     int* __restrict__ bucketBase) {
  __shared__ int sm[1024];
  int t = threadIdx.x;
  int v = (t < NBUCKETS) ? min(gCursor[t], BCAP) : 0;
  sm[t] = v;
  __syncthreads();
  for (int off = 1; off < 1024; off <<= 1) {
    int x = (t >= off) ? sm[t - off] : 0;
    __syncthreads();
    sm[t] += x;
    __syncthreads();
  }
  bucketBase[t] = sm[t] - v;
  if (t == NBUCKETS - 1) bucketBase[NBUCKETS] = sm[t];
}

// ---------------- stage 2: per-bucket counting sort by (dstLocal, srcCoarse) ----------------

__global__ __launch_bounds__(256) void csort_kernel(const int* __restrict__ gCursor,
                                                    const int* __restrict__ bucketBase,
                                                    const uint_t* __restrict__ gPairs,
                                                    int* __restrict__ rowptr,
                                                    int* __restrict__ ssrc) {
  __shared__ uint_t vals[BCAP];
  __shared__ int ssl[BCAP];
  __shared__ int hist[1024];
  __shared__ int cur[1024];
  __shared__ int wsum[4];

  const int b = blockIdx.x, t = threadIdx.x;
  const int cnt = min(gCursor[b], BCAP);
  const int base = bucketBase[b];
  const int n0 = b << 7;
  const int nn = min(128, N_NODES - n0);

  for (int i = t; i < 1024; i += 256) hist[i] = 0;
  __syncthreads();
  for (int i = t; i < cnt; i += 256) {
    uint_t v = gPairs[b * BCAP + i];
    vals[i] = v;
    int bin = (int)((v >> 17) & 127u) * 8 + (int)((v & 0x1FFFFu) >> 14);
    atomicAdd(&hist[bin], 1);
  }
  __syncthreads();

  const int b4 = t * 4;
  int h0 = hist[b4], h1 = hist[b4 + 1], h2 = hist[b4 + 2], h3 = hist[b4 + 3];
  int tsum = h0 + h1 + h2 + h3;
  int lane = t & 63, wid = t >> 6;
  int inc = tsum;
  #pragma unroll
  for (int off = 1; off < 64; off <<= 1) {
    int v = __shfl_up(inc, off);
    if (lane >= off) inc += v;
  }
  if (lane == 63) wsum[wid] = inc;
  __syncthreads();
  int wadd = 0;
  for (int w = 0; w < wid; ++w) wadd += wsum[w];
  int ex = wadd + inc - tsum;
  #pragma unroll
  for (int q = 0; q < 4; ++q) {
    int bin = b4 + q;
    cur[bin] = ex;
    if ((bin & 7) == 0) {
      int dl = bin >> 3;
      if (dl < nn) rowptr[n0 + dl] = base + ex;
    }
    ex += hist[bin];
  }
  if (b == NBUCKETS - 1 && t == 0) rowptr[N_NODES] = base + cnt;
  __syncthreads();

  for (int i = t; i < cnt; i += 256) {
    uint_t v = vals[i];
    int bin = (int)((v >> 17) & 127u) * 8 + (int)((v & 0x1FFFFu) >> 14);
    int p = atomicAdd(&cur[bin], 1);
    ssl[p] = (int)(v & 0x1FFFFu);
  }
  __syncthreads();
  for (int i = t; i < cnt; i += 256) ssrc[base + i] = ssl[i];
}

// ---------------- aggregation: 2 nodes/wave, depth-2 pipeline, packed f32 adds ----------------
// lane l: edge slot l>>3 (0..7), dims ((l&7)*8) as uint4. Accumulators are
// float2 vectors -> v_pk_add_f32; hi unpack is a single AND.

#define ACCP(A, R)          \
  A[0] += bfpair(R.x);      \
  A[1] += bfpair(R.y);      \
  A[2] += bfpair(R.z);      \
  A[3] += bfpair(R.w);

__global__ __launch_bounds__(256) void agg_kernel(const ushort_t* __restrict__ h,
                                                  const int* __restrict__ rowptr,
                                                  const int* __restrict__ ssrc,
                                                  ushort_t* __restrict__ zb) {
  int pair = blockIdx.x * 4 + (threadIdx.x >> 6);
  int l = threadIdx.x & 63;
  int n0 = pair * 2;
  if (n0 >= N_NODES) return;
  int n1 = n0 + 1;                      // N even -> always < N_NODES
  int sub = l >> 3;
  int dp = (l & 7) << 3;

  float2v a0[4], a1[4];
  #pragma unroll
  for (int i = 0; i < 4; ++i) { a0[i] = (float2v){0.f, 0.f}; a1[i] = (float2v){0.f, 0.f}; }

  int s0 = rowptr[n0], e0 = rowptr[n0 + 1];
  int s1 = e0,         e1 = rowptr[n1 + 1];   // rowptr contiguous

  if (sub == 0) {
    uint4 r = *(const uint4*)(h + (size_t)n0 * DIM + dp);
    uint4 q = *(const uint4*)(h + (size_t)n1 * DIM + dp);
    ACCP(a0, r);
    ACCP(a1, q);
  }

  const uint4 zz = make_uint4(0u, 0u, 0u, 0u);
  int j0 = s0 + sub, j1 = s1 + sub;
  uint4 r0 = zz, r1 = zz;
  if (j0 < e0) r0 = *(const uint4*)(h + (size_t)ssrc[j0] * DIM + dp);
  if (j1 < e1) r1 = *(const uint4*)(h + (size_t)ssrc[j1] * DIM + dp);

  int iters = (max(e0 - s0, e1 - s1) + 7) >> 3;
  for (int it = 1; it < iters; ++it) {
    int nj0 = j0 + 8, nj1 = j1 + 8;
    uint4 p0 = zz, p1 = zz;
    if (nj0 < e0) p0 = *(const uint4*)(h + (size_t)ssrc[nj0] * DIM + dp);
    if (nj1 < e1) p1 = *(const uint4*)(h + (size_t)ssrc[nj1] * DIM + dp);
    ACCP(a0, r0);
    ACCP(a1, r1);
    r0 = p0; r1 = p1;
    j0 = nj0; j1 = nj1;
  }
  ACCP(a0, r0);
  ACCP(a1, r1);

  #pragma unroll
  for (int i = 0; i < 4; ++i) {
    #pragma unroll
    for (int m = 8; m <= 32; m <<= 1) {
      float2v t0 = (float2v){__shfl_xor(a0[i].x, m), __shfl_xor(a0[i].y, m)};
      float2v t1 = (float2v){__shfl_xor(a1[i].x, m), __shfl_xor(a1[i].y, m)};
      a0[i] += t0;
      a1[i] += t1;
    }
  }

  if (sub == 0) {
    uint4 o0, o1;
    o0.x = pack2(a0[0].x, a0[0].y); o0.y = pack2(a0[1].x, a0[1].y);
    o0.z = pack2(a0[2].x, a0[2].y); o0.w = pack2(a0[3].x, a0[3].y);
    o1.x = pack2(a1[0].x, a1[0].y); o1.y = pack2(a1[1].x, a1[1].y);
    o1.z = pack2(a1[2].x, a1[2].y); o1.w = pack2(a1[3].x, a1[3].y);
    *(uint4*)(zb + (size_t)n0 * DIM + dp) = o0;
    *(uint4*)(zb + (size_t)n1 * DIM + dp) = o1;
  }
}

// ---------------- MFMA MLP: pre-transposed bf16 weights, BN folded ----------------

__global__ __launch_bounds__(256) void mlp_kernel(const ushort_t* __restrict__ zb,
                                                  ushort_t* __restrict__ hout,
                                                  const ushort_t* __restrict__ W1bT,
                                                  const float* __restrict__ b1p,
                                                  const ushort_t* __restrict__ W2bT,
                                                  const float* __restrict__ b2) {
  __shared__ ushort_t zs[128 * WSTR];
  __shared__ ushort_t wt1[64 * WSTR];
  __shared__ ushort_t wt2[64 * WSTR];

  const int t = threadIdx.x;
  const int base = blockIdx.x * 128;

  #pragma unroll
  for (int i = 0; i < 4; ++i) {
    int f = i * 256 + t;
    int row = f >> 3, seg = (f & 7) << 3;
    int gn = base + row;
    if (gn >= N_NODES) gn = N_NODES - 1;
    *(uint4*)(zs + row * WSTR + seg) = *(const uint4*)(zb + (size_t)gn * DIM + seg);
  }
  #pragma unroll
  for (int i = 0; i < 2; ++i) {
    int f = i * 256 + t;                 // 512 uint4 slots per matrix
    int n = f >> 3, kseg = (f & 7) << 3;
    *(uint4*)(wt1 + n * WSTR + kseg) = *(const uint4*)(W1bT + n * 64 + kseg);
    *(uint4*)(wt2 + n * WSTR + kseg) = *(const uint4*)(W2bT + n * 64 + kseg);
  }
  __syncthreads();

  const int lane = t & 63;
  const int w = t >> 6;
  const int lr = lane & 15;
  const int kc = lane >> 4;

  float o_[4], bb_[4];
  #pragma unroll
  for (int nt = 0; nt < 4; ++nt) {
    int od = nt * 16 + lr;
    o_[nt] = b1p[od];
    bb_[nt] = b2[od];
  }

  float4v acc[2][4];
  #pragma unroll
  for (int mt = 0; mt < 2; ++mt)
    #pragma unroll
    for (int nt = 0; nt < 4; ++nt)
      acc[mt][nt] = (float4v){0.f, 0.f, 0.f, 0.f};

  #pragma unroll
  for (int k0 = 0; k0 < 2; ++k0) {
    short8v bfr[4];
    #pragma unroll
    for (int nt = 0; nt < 4; ++nt)
      bfr[nt] = *(short8v*)(wt1 + (nt * 16 + lr) * WSTR + k0 * 32 + kc * 8);
    #pragma unroll
    for (int mt = 0; mt < 2; ++mt) {
      short8v afr = *(short8v*)(zs + ((w * 2 + mt) * 16 + lr) * WSTR + k0 * 32 + kc * 8);
      #pragma unroll
      for (int nt = 0; nt < 4; ++nt)
        acc[mt][nt] = __builtin_amdgcn_mfma_f32_16x16x32_bf16(afr, bfr[nt], acc[mt][nt], 0, 0, 0);
    }
  }

  #pragma unroll
  for (int mt = 0; mt < 2; ++mt)
    #pragma unroll
    for (int nt = 0; nt < 4; ++nt)
      #pragma unroll
      for (int r = 0; r < 4; ++r) {
        float v = acc[mt][nt][r] + o_[nt];
        v = v > 0.f ? v : 0.f;
        int node = (w * 2 + mt) * 16 + kc * 4 + r;
        zs[node * WSTR + nt * 16 + lr] = f2bf(v);
      }

  #pragma unroll
  for (int mt = 0; mt < 2; ++mt)
    #pragma unroll
    for (int nt = 0; nt < 4; ++nt)
      acc[mt][nt] = (float4v){0.f, 0.f, 0.f, 0.f};

  #pragma unroll
  for (int k0 = 0; k0 < 2; ++k0) {
    short8v bfr[4];
    #pragma unroll
    for (int nt = 0; nt < 4; ++nt)
      bfr[nt] = *(short8v*)(wt2 + (nt * 16 + lr) * WSTR + k0 * 32 + kc * 8);
    #pragma unroll
    for (int mt = 0; mt < 2; ++mt) {
      short8v afr = *(short8v*)(zs + ((w * 2 + mt) * 16 + lr) * WSTR + k0 * 32 + kc * 8);
      #pragma unroll
      for (int nt = 0; nt < 4; ++nt)
        acc[mt][nt] = __builtin_amdgcn_mfma_f32_16x16x32_bf16(afr, bfr[nt], acc[mt][nt], 0, 0, 0);
    }
  }

  #pragma unroll
  for (int mt = 0; mt < 2; ++mt)
    #pragma unroll
    for (int nt = 0; nt < 4; ++nt)
      #pragma unroll
      for (int r = 0; r < 4; ++r) {
        float v = acc[mt][nt][r] + bb_[nt];
        v = v > 0.f ? v : 0.f;
        int node = (w * 2 + mt) * 16 + kc * 4 + r;
        zs[node * WSTR + nt * 16 + lr] = f2bf(v);
      }
  __syncthreads();

  #pragma unroll
  for (int i = 0; i < 4; ++i) {
    int f = i * 256 + t;
    int row = f >> 3, seg = (f & 7) << 3;
    int gn = base + row;
    if (gn < N_NODES)
      *(uint4*)(hout + (size_t)gn * DIM + seg) = *(const uint4*)(zs + row * WSTR + seg);
  }
}

// ---------------- pool: partial sums (batch sorted) + tiny head ----------------

__global__ __launch_bounds__(256) void pool_partial_kernel(const ushort_t* __restrict__ h,
                                                           const int* __restrict__ batch,
                                                           float* __restrict__ pooled) {
  int r0 = blockIdx.x * POOL_CH;
  int rend = min(r0 + POOL_CH, N_NODES);
  int w = threadIdx.x >> 6, d = threadIdx.x & 63;
  float acc = 0.f;
  int curg = -1;
  for (int i = r0 + w; i < rend; i += 4) {
    int g = batch[i];
    if (g != curg) {
      if (curg >= 0) atomicAdd(&pooled[curg * DIM + d], acc);
      acc = 0.f;
      curg = g;
    }
    acc += bf2f((uint_t)h[i * DIM + d]);
  }
  if (curg >= 0) atomicAdd(&pooled[curg * DIM + d], acc);
}

__global__ __launch_bounds__(256) void head_kernel(const float* __restrict__ pooled,
                                                   const float* __restrict__ lw,
                                                   const float* __restrict__ lb,
                                                   float* __restrict__ out) {
  int idx = blockIdx.x * 256 + threadIdx.x;
  if (idx >= N_GRAPHS * DIM) return;
  int g = idx >> 6, d = idx & 63;
  float o = lb[d];
  #pragma unroll 8
  for (int k = 0; k < 64; ++k) o = fmaf(pooled[g * 64 + k], lw[k * 64 + d], o);
  out[idx] = fmaxf(o, 0.f);
}

// ---------------- host ----------------

extern "C" void kernel_launch(void* const* d_in, const int* in_sizes, int n_in,
                              void* d_out, int out_size, void* d_ws, size_t ws_size,
                              hipStream_t stream) {
  const float* x      = (const float*)d_in[0];
  const int*   ei     = (const int*)d_in[1];
  const int*   srcp   = ei;
  const int*   dstp   = ei + N_EDGES;
  const int*   batch  = (const int*)d_in[2];
  const float* W1s    = (const float*)d_in[3];
  const float* b1s    = (const float*)d_in[4];
  const float* gammas = (const float*)d_in[5];
  const float* betas  = (const float*)d_in[6];
  const float* W2s    = (const float*)d_in[7];
  const float* b2s    = (const float*)d_in[8];
  const float* lin1_w = (const float*)d_in[9];
  const float* lin1_b = (const float*)d_in[10];

  char* p = (char*)d_ws;
  ushort_t* xb     = (ushort_t*)p; p += (size_t)N_NODES * DIM * 2;      // 12.8 MB
  ushort_t* h1     = (ushort_t*)p; p += (size_t)N_NODES * DIM * 2;      // 12.8 MB
  ushort_t* zbuf   = (ushort_t*)p; p += (size_t)N_NODES * DIM * 2;      // 12.8 MB
  uint_t*   gPairs = (uint_t*)p;   p += (size_t)NBUCKETS * BCAP * 4;    // 6.4 MB
  int*      ssrc   = (int*)p;      p += (size_t)N_EDGES * 4;            // 4.8 MB
  int*      rowptr = (int*)p;      p += 100352 * sizeof(int);
  int*      gCursor    = (int*)p;  p += 4096;
  int*      bucketBase = (int*)p;  p += 4096;
  ushort_t* W1bT   = (ushort_t*)p; p += N_LAYERS * 4096 * 2;
  ushort_t* W2bT   = (ushort_t*)p; p += N_LAYERS * 4096 * 2;
  float*    b1p    = (float*)p;    p += N_LAYERS * 64 * sizeof(float);
  float*    pooled = (float*)p;

  hipMemsetAsync(gCursor, 0, 1024 * sizeof(int), stream);
  hipMemsetAsync(pooled, 0, N_GRAPHS * DIM * sizeof(float), stream);
  prep_kernel<<<CONV_BLOCKS + (N_LAYERS * 4096 + 255) / 256, 256, 0, stream>>>(
      x, xb, W1s, b1s, gammas, betas, W2s, W1bT, W2bT, b1p);

  const int BIN_BLOCKS = (N_EDGES + CHUNK - 1) / CHUNK;   // 147
  bin_kernel<<<BIN_BLOCKS, 256, 0, stream>>>(srcp, dstp, gCursor, gPairs);
  bscan_kernel<<<1, 1024, 0, stream>>>(gCursor, bucketBase);
  csort_kernel<<<NBUCKETS, 256, 0, stream>>>(gCursor, bucketBase, gPairs, rowptr, ssrc);

  const int AGG_BLOCKS = (N_NODES / 2 + 3) / 4;      // 12500 (pairs, 4 per block)
  const int MLP_BLOCKS = NBUCKETS;                   // 782

  const ushort_t* hin = xb;
  for (int l = 0; l < N_LAYERS; ++l) {
    ushort_t* hout = (l & 1) ? xb : h1;
    agg_kernel<<<AGG_BLOCKS, 256, 0, stream>>>(hin, rowptr, ssrc, zbuf);
    mlp_kernel<<<MLP_BLOCKS, 256, 0, stream>>>(zbuf, hout,
        W1bT + (size_t)l * 4096, b1p + (size_t)l * 64,
        W2bT + (size_t)l * 4096, b2s + (size_t)l * DIM);
    hin = hout;
  }

  pool_partial_kernel<<<POOL_BLOCKS, 256, 0, stream>>>(h1, batch, pooled);
  head_kernel<<<(N_GRAPHS * DIM + 255) / 256, 256, 0, stream>>>(pooled, lin1_w, lin1_b, (float*)d_out);
}